// Round 4
// baseline (866.553 us; speedup 1.0000x reference)
//
#include <hip/hip_runtime.h>

// ForgetMult: h_t = f_t*x_t + (1-f_t)*h_{t-1}, independent per (b,h) channel.
// R3: latency model from R0/R1/R2 says delivered BW == in-flight bytes / L_eff
// (L_eff ~800cy), and scalar loads cap at vmcnt<=63 outstanding = 16 KB/wave.
// Fix: float2 loads (512 B per wave-op -> 32 KB possible) + TRIPLE-buffered
// register pipeline so the load pipe never drains (R2's burst-then-wait had a
// full-latency bubble every group). One thread per 2 channels: 16384 threads
// = 256 blocks x 64 = 1 wave/CU, all CUs covered.
//
// Pipeline: buffers A,B,C of U=16 float2 timesteps (32 loads = 16 KB each).
// Each phase: prefetch one group 2 phases ahead, sched_barrier(0) (pins the
// loads BEFORE the compute - R2's VGPR=68 proved this mechanism works), then
// run the FMA chain on a buffer loaded 2 phases ago. Sustained outstanding
// ~32 KB/CU >= 20 KB needed for 6.3 TB/s at L_eff~800cy.
//
// __launch_bounds__(64,2): 256-VGPR cap; ~205 VGPRs used (3x64 data + addr).

constexpr int U = 16;  // float2 timesteps per group; nG = T/U = 128

__global__ __launch_bounds__(64, 2) void forget_mult_kernel(
    const float2* __restrict__ x, const float2* __restrict__ f,
    const float2* __restrict__ h0, float2* __restrict__ out,
    int T, int H2) {
  const int tid = blockIdx.x * blockDim.x + threadIdx.x;  // [0, B*H/2)
  const int b = tid / H2;
  const int h = tid - b * H2;
  const int base = b * T * H2 + h;  // float2 units; max ~33.5M < 2^31

  float2 hv = h0[tid];

  float2 xA[U], fA[U], xB[U], fB[U], xC[U], fC[U];

  const int nG = T / U;  // 128

#define LOADG(XBUF, FBUF, gidx)                    \
  {                                                \
    const int gb = base + (gidx) * (U * H2);       \
    _Pragma("unroll") for (int u = 0; u < U; ++u) { \
      XBUF[u] = x[gb + u * H2];                    \
      FBUF[u] = f[gb + u * H2];                    \
    }                                              \
  }

#define COMPG(XBUF, FBUF, gidx)                     \
  {                                                 \
    const int gb = base + (gidx) * (U * H2);        \
    _Pragma("unroll") for (int u = 0; u < U; ++u) { \
      const float2 xv = XBUF[u], fv = FBUF[u];      \
      hv.x = fmaf(1.0f - fv.x, hv.x, fv.x * xv.x);  \
      hv.y = fmaf(1.0f - fv.y, hv.y, fv.y * xv.y);  \
      out[gb + u * H2] = hv;                        \
    }                                               \
  }

  // Prologue: groups 0,1 in flight.
  LOADG(xA, fA, 0)
  LOADG(xB, fB, 1)

  // nG=128 = 3*42+2: last iter g=126 computes A(126),B(127), skips C.
  for (int g = 0; g < nG; g += 3) {
    if (g + 2 < nG) LOADG(xC, fC, g + 2)
    __builtin_amdgcn_sched_barrier(0);
    COMPG(xA, fA, g)
    if (g + 3 < nG) LOADG(xA, fA, g + 3)
    __builtin_amdgcn_sched_barrier(0);
    if (g + 1 < nG) COMPG(xB, fB, g + 1)
    if (g + 4 < nG) LOADG(xB, fB, g + 4)
    __builtin_amdgcn_sched_barrier(0);
    if (g + 2 < nG) COMPG(xC, fC, g + 2)
  }
#undef LOADG
#undef COMPG
}

extern "C" void kernel_launch(void* const* d_in, const int* in_sizes, int n_in,
                              void* d_out, int out_size, void* d_ws, size_t ws_size,
                              hipStream_t stream) {
  const float2* x = (const float2*)d_in[0];
  const float2* f = (const float2*)d_in[1];
  const float2* h0 = (const float2*)d_in[2];
  float2* out = (float2*)d_out;

  const int BH = in_sizes[2];      // B*H = 32768
  const int T = in_sizes[0] / BH;  // 2048
  const int H = 1024;              // per setup_inputs()
  const int H2 = H / 2;            // 512 float2 per row

  const int threads = BH / 2;      // 16384
  const int block = 64;
  const int grid = threads / block;  // 256 blocks -> 1 wave/CU on 256 CUs
  forget_mult_kernel<<<grid, block, 0, stream>>>(x, f, h0, out, T, H2);
}

// Round 5
// 167.999 us; speedup vs baseline: 5.1581x; 5.1581x over previous
//
#include <hip/hip_runtime.h>

// ForgetMult: h_t = f_t*x_t + (1-f_t)*h_{t-1}, independent per (b,h) channel.
// R4: R3's double-issue pipeline, sized to NOT spill (R3: 192 data regs vs
// 128-VGPR allocation -> scratch traffic, WRITE_SIZE +52 MB, 5x slower).
//
// Scalar mapping: one thread per channel, 32768 threads = 512 blocks x 64
// = 2 waves/CU. Double-buffered register pipeline, U=16 timesteps/group:
// data regs = 2 bufs x (16 x + 16 f) = 64 VGPRs (~90 total, well under cap).
// Program order per phase: PREFETCH(next group, 32 loads = 8 KB/wave) ->
// sched_barrier(0) -> COMPUTE(current group). The compute's waitcnt only
// drains the CURRENT group's loads, so the next group's 8 KB stays in
// flight: 16 KB/CU sustained / ~330ns latency = ~48 GB/s/CU -> HBM-bound,
// not latency-bound (R0 had only ~12 loads in flight -> 4.7 TB/s).
//
// Same FMA formula as R0/R2 (bit-exact vs harness ref), same (64,2)
// launch-bounds class that passed twice. Avoids R1's (64,1) config.

constexpr int U = 16;  // timesteps per group; nG = T/U = 128 (even)

__global__ __launch_bounds__(64, 2) void forget_mult_kernel(
    const float* __restrict__ x, const float* __restrict__ f,
    const float* __restrict__ h0, float* __restrict__ out,
    int T, int H) {
  const int tid = blockIdx.x * blockDim.x + threadIdx.x;  // [0, B*H)
  const int b = tid / H;
  const int h = tid - b * H;
  const int base = b * T * H + h;  // B*T*H = 67,108,864 < 2^31

  float hv = h0[tid];

  float xA[U], fA[U], xB[U], fB[U];

  const int nG = T / U;  // 128

#define LOADG(XBUF, FBUF, gidx)                     \
  {                                                 \
    const int gb = base + (gidx) * (U * H);         \
    _Pragma("unroll") for (int u = 0; u < U; ++u) { \
      XBUF[u] = x[gb + u * H];                      \
      FBUF[u] = f[gb + u * H];                      \
    }                                               \
  }

#define COMPG(XBUF, FBUF, gidx)                       \
  {                                                   \
    const int gb = base + (gidx) * (U * H);           \
    _Pragma("unroll") for (int u = 0; u < U; ++u) {   \
      const float xv = XBUF[u], fv = FBUF[u];         \
      hv = fmaf(1.0f - fv, hv, fv * xv);              \
      out[gb + u * H] = hv;                           \
    }                                                 \
  }

  // Prologue: group 0 in flight.
  LOADG(xA, fA, 0)

  for (int g = 0; g < nG; g += 2) {
    if (g + 1 < nG) LOADG(xB, fB, g + 1)
    __builtin_amdgcn_sched_barrier(0);  // keep B's loads ahead of A's compute
    COMPG(xA, fA, g)
    if (g + 2 < nG) LOADG(xA, fA, g + 2)
    __builtin_amdgcn_sched_barrier(0);
    if (g + 1 < nG) COMPG(xB, fB, g + 1)
  }
#undef LOADG
#undef COMPG
}

extern "C" void kernel_launch(void* const* d_in, const int* in_sizes, int n_in,
                              void* d_out, int out_size, void* d_ws, size_t ws_size,
                              hipStream_t stream) {
  const float* x = (const float*)d_in[0];
  const float* f = (const float*)d_in[1];
  const float* h0 = (const float*)d_in[2];
  float* out = (float*)d_out;

  const int BH = in_sizes[2];      // B*H = 32768
  const int T = in_sizes[0] / BH;  // 2048
  const int H = 1024;              // per setup_inputs()

  const int block = 64;
  const int grid = BH / block;     // 512 blocks -> 2 waves/CU on 256 CUs
  forget_mult_kernel<<<grid, block, 0, stream>>>(x, f, h0, out, T, H);
}

// Round 6
// 166.567 us; speedup vs baseline: 5.2024x; 1.0086x over previous
//
#include <hip/hip_runtime.h>

// ForgetMult: h_t = f_t*x_t + (1-f_t)*h_{t-1}, independent per (b,h) channel.
// R5: decisive latency test. R0(6KB/CU in flight)=R4(16KB/CU)=~162us because
// both sit at/below the latency-BW product: 6.3 TB/s needs ~20 KB/CU in
// flight at L_eff~800cy. This round: scalar TRIPLE buffer (R3's bit-exact
// structure, but scalar so 96 data VGPRs fit the 128-VGPR allocation that
// (64,2) empirically produces -- R3's float2 needed 192 and spilled).
// In flight during each compute phase: 2 groups x 32 loads (vmcnt-capped 63)
// ~= 16 KB/wave x 2 waves/CU = 32 KB/CU > 20 KB requirement, first time.
//
// One thread per channel: 32768 threads = 512 blocks x 64 = 2 waves/CU.
// If this is flat at ~160us, the 2R+1W 4KB-strided stream pattern itself
// plateaus at ~5 TB/s (~80% of the float4-copy ceiling) -> roofline.

constexpr int U = 16;  // timesteps per group; nG = T/U = 128

__global__ __launch_bounds__(64, 2) void forget_mult_kernel(
    const float* __restrict__ x, const float* __restrict__ f,
    const float* __restrict__ h0, float* __restrict__ out,
    int T, int H) {
  const int tid = blockIdx.x * blockDim.x + threadIdx.x;  // [0, B*H)
  const int b = tid / H;
  const int h = tid - b * H;
  const int base = b * T * H + h;  // B*T*H = 67,108,864 < 2^31

  float hv = h0[tid];

  float xA[U], fA[U], xB[U], fB[U], xC[U], fC[U];  // 96 VGPRs of data

  const int nG = T / U;  // 128

#define LOADG(XBUF, FBUF, gidx)                     \
  {                                                 \
    const int gb = base + (gidx) * (U * H);         \
    _Pragma("unroll") for (int u = 0; u < U; ++u) { \
      XBUF[u] = x[gb + u * H];                      \
      FBUF[u] = f[gb + u * H];                      \
    }                                               \
  }

#define COMPG(XBUF, FBUF, gidx)                     \
  {                                                 \
    const int gb = base + (gidx) * (U * H);         \
    _Pragma("unroll") for (int u = 0; u < U; ++u) { \
      const float xv = XBUF[u], fv = FBUF[u];       \
      hv = fmaf(1.0f - fv, hv, fv * xv);            \
      out[gb + u * H] = hv;                         \
    }                                               \
  }

  // Prologue: keep 2 groups in flight at all times.
  LOADG(xA, fA, 0)
  LOADG(xB, fB, 1)

  // nG = 128 = 3*42 + 2: last iteration computes A(126), B(127), skips C.
  for (int g = 0; g < nG; g += 3) {
    if (g + 2 < nG) LOADG(xC, fC, g + 2)
    __builtin_amdgcn_sched_barrier(0);
    COMPG(xA, fA, g)
    if (g + 3 < nG) LOADG(xA, fA, g + 3)
    __builtin_amdgcn_sched_barrier(0);
    if (g + 1 < nG) COMPG(xB, fB, g + 1)
    if (g + 4 < nG) LOADG(xB, fB, g + 4)
    __builtin_amdgcn_sched_barrier(0);
    if (g + 2 < nG) COMPG(xC, fC, g + 2)
  }
#undef LOADG
#undef COMPG
}

extern "C" void kernel_launch(void* const* d_in, const int* in_sizes, int n_in,
                              void* d_out, int out_size, void* d_ws, size_t ws_size,
                              hipStream_t stream) {
  const float* x = (const float*)d_in[0];
  const float* f = (const float*)d_in[1];
  const float* h0 = (const float*)d_in[2];
  float* out = (float*)d_out;

  const int BH = in_sizes[2];      // B*H = 32768
  const int T = in_sizes[0] / BH;  // 2048
  const int H = 1024;              // per setup_inputs()

  const int block = 64;
  const int grid = BH / block;     // 512 blocks -> 2 waves/CU on 256 CUs
  forget_mult_kernel<<<grid, block, 0, stream>>>(x, f, h0, out, T, H);
}